// Round 2
// baseline (2534.136 us; speedup 1.0000x reference)
//
#include <hip/hip_runtime.h>
#include <hip/hip_bf16.h>

typedef __hip_bfloat16 bf16;

static __device__ __forceinline__ float b2f(bf16 v) { return __bfloat162float(v); }

// dual-mode float load: f32 ? float buffer : bf16 buffer (same element index)
static __device__ __forceinline__ float ldf(const void* p, long long i, bool f32) {
    return f32 ? ((const float*)p)[i] : __bfloat162float(((const bf16*)p)[i]);
}

// ---------------------------------------------------------------- encoding sniffer
// flags[0]: x is fp32?   flags[1]: weights are fp32?   flags[2]: edge_index is int64?
__global__ void sniff_kernel(const void* __restrict__ x, const void* __restrict__ w,
                             const int* __restrict__ ei, int E, int* __restrict__ flags) {
    __shared__ int cnt;
    if (threadIdx.x == 0) cnt = 0;
    __syncthreads();
    if (blockIdx.x < 2) {
        // Interpret raw half-words as bf16. A true bf16 N(0,sigma) buffer never has
        // exponent >= 0xA0 (|v| >= 2^33). An fp32 buffer's low half-words have
        // ~uniform exponent bits -> ~37% anomalies.
        const unsigned short* u = (const unsigned short*)(blockIdx.x == 0 ? x : w);
        int bad = 0;
        for (int i = threadIdx.x; i < 4096; i += 256) {
            unsigned e = (u[i] >> 7) & 0xFF;
            if (e >= 0xA0) bad++;
        }
        atomicAdd(&cnt, bad);
        __syncthreads();
        if (threadIdx.x == 0) flags[blockIdx.x] = (cnt > 16) ? 1 : 0;
    } else {
        // int64 edge_index => every odd 32-bit word (high word) is 0 (values < 1e5).
        int nz = 0;
        for (int i = threadIdx.x; i < 1024; i += 256)
            if (ei[2 * i + 1] != 0) nz++;
        atomicAdd(&cnt, nz);
        __syncthreads();
        if (threadIdx.x == 0) flags[2] = (cnt == 0) ? 1 : 0;
    }
}

static __device__ __forceinline__ int ld_src(const int* ei, int E, int e, bool i64) {
    return i64 ? ei[2 * e] : ei[e];
}
static __device__ __forceinline__ int ld_dst(const int* ei, int E, int e, bool i64) {
    return i64 ? ei[2 * (E + e)] : ei[E + e];
}

// ---------------------------------------------------------------- degree
__global__ void deg_kernel(const int* __restrict__ ei, int E, const int* __restrict__ flags,
                           float* __restrict__ deg) {
    int i = blockIdx.x * blockDim.x + threadIdx.x;
    if (i >= E) return;
    bool i64 = flags[2] != 0;
    int d = ld_dst(ei, E, i, i64);
    atomicAdd(&deg[d], 1.0f);
}

// deg -> dinv in place: dinv = rsqrt(deg + 1)
__global__ void dinv_kernel(float* __restrict__ deg, int N) {
    int i = blockIdx.x * blockDim.x + threadIdx.x;
    if (i < N) deg[i] = rsqrtf(deg[i] + 1.0f);
}

// ---------------------------------------------------------------- GEMM1: x[N,128] @ W1[128,64] -> h1x[N,64]
__global__ void gemm1_kernel(const void* __restrict__ x, const void* __restrict__ W1,
                             const int* __restrict__ flags, float* __restrict__ h1x, int N) {
    __shared__ float Ws[128 * 64];
    __shared__ float Xs[4 * 128];
    bool fx = flags[0] != 0, fw = flags[1] != 0;
    for (int i = threadIdx.x; i < 128 * 64; i += 256) Ws[i] = ldf(W1, i, fw);
    int base = blockIdx.x * 4;
    for (int i = threadIdx.x; i < 4 * 128; i += 256) {
        int r = i >> 7, k = i & 127;
        int n = base + r;
        Xs[i] = (n < N) ? ldf(x, (long long)n * 128 + k, fx) : 0.f;
    }
    __syncthreads();
    int ln = threadIdx.x >> 6, c = threadIdx.x & 63;
    int n = base + ln;
    if (n >= N) return;
    float acc = 0.f;
    const float* xr = &Xs[ln * 128];
#pragma unroll 8
    for (int k = 0; k < 128; k++) acc = fmaf(xr[k], Ws[k * 64 + c], acc);
    h1x[(long long)n * 64 + c] = acc;
}

// ---------------------------------------------------------------- scatter layer 1 (64 ch)
__global__ void scatter1_kernel(const int* __restrict__ ei, int E, const int* __restrict__ flags,
                                const float* __restrict__ dinv, const float* __restrict__ h1x,
                                float* __restrict__ agg1) {
    long long t = (long long)blockIdx.x * blockDim.x + threadIdx.x;
    int e = (int)(t >> 4);
    if (e >= E) return;
    bool i64 = flags[2] != 0;
    int g = (int)(t & 15);
    int s = ld_src(ei, E, e, i64), d = ld_dst(ei, E, e, i64);
    float nm = dinv[s] * dinv[d];
    float4 v = *reinterpret_cast<const float4*>(&h1x[(long long)s * 64 + g * 4]);
    float* o = &agg1[(long long)d * 64 + g * 4];
    atomicAdd(o + 0, v.x * nm);
    atomicAdd(o + 1, v.y * nm);
    atomicAdd(o + 2, v.z * nm);
    atomicAdd(o + 3, v.w * nm);
}

// h1 = relu(agg1 + h1x*dinv^2 + b1), in place into agg1
__global__ void h1fin_kernel(float* __restrict__ agg1, const float* __restrict__ h1x,
                             const float* __restrict__ dinv, const void* __restrict__ b1,
                             const int* __restrict__ flags, int N) {
    long long i = (long long)blockIdx.x * blockDim.x + threadIdx.x;
    if (i >= (long long)N * 64) return;
    bool fw = flags[1] != 0;
    int n = (int)(i >> 6), c = (int)(i & 63);
    float dv = dinv[n];
    float v = agg1[i] + h1x[i] * dv * dv + ldf(b1, c, fw);
    agg1[i] = v > 0.f ? v : 0.f;
}

// ---------------------------------------------------------------- GEMM2: h1[N,64] @ W2[64,32] -> h2x[N,32]
__global__ void gemm2_kernel(const float* __restrict__ h1, const void* __restrict__ W2,
                             const int* __restrict__ flags, float* __restrict__ h2x, int N) {
    __shared__ float Ws[64 * 32];
    __shared__ float Xs[8 * 64];
    bool fw = flags[1] != 0;
    for (int i = threadIdx.x; i < 64 * 32; i += 256) Ws[i] = ldf(W2, i, fw);
    int base = blockIdx.x * 8;
    for (int i = threadIdx.x; i < 8 * 64; i += 256) {
        int r = i >> 6, k = i & 63;
        int n = base + r;
        Xs[i] = (n < N) ? h1[(long long)n * 64 + k] : 0.f;
    }
    __syncthreads();
    int ln = threadIdx.x >> 5, c = threadIdx.x & 31;
    int n = base + ln;
    if (n >= N) return;
    float acc = 0.f;
    const float* xr = &Xs[ln * 64];
#pragma unroll 8
    for (int k = 0; k < 64; k++) acc = fmaf(xr[k], Ws[k * 32 + c], acc);
    h2x[(long long)n * 32 + c] = acc;
}

// ---------------------------------------------------------------- scatter layer 2 (32 ch)
__global__ void scatter2_kernel(const int* __restrict__ ei, int E, const int* __restrict__ flags,
                                const float* __restrict__ dinv, const float* __restrict__ h2x,
                                float* __restrict__ agg2) {
    long long t = (long long)blockIdx.x * blockDim.x + threadIdx.x;
    int e = (int)(t >> 3);
    if (e >= E) return;
    bool i64 = flags[2] != 0;
    int g = (int)(t & 7);
    int s = ld_src(ei, E, e, i64), d = ld_dst(ei, E, e, i64);
    float nm = dinv[s] * dinv[d];
    float4 v = *reinterpret_cast<const float4*>(&h2x[(long long)s * 32 + g * 4]);
    float* o = &agg2[(long long)d * 32 + g * 4];
    atomicAdd(o + 0, v.x * nm);
    atomicAdd(o + 1, v.y * nm);
    atomicAdd(o + 2, v.z * nm);
    atomicAdd(o + 3, v.w * nm);
}

// ---------------------------------------------------------------- final: cat[x,h1,h2] @ Wl + bl -> log_softmax
__global__ void final_kernel(const void* __restrict__ x, const float* __restrict__ h1,
                             const float* __restrict__ agg2, const float* __restrict__ h2x,
                             const float* __restrict__ dinv, const void* __restrict__ b2,
                             const void* __restrict__ Wl, const void* __restrict__ bl,
                             const int* __restrict__ flags, void* __restrict__ out, int N) {
    __shared__ float Ws[224 * 32];
    __shared__ float Cs[8 * 224];
    bool fx = flags[0] != 0, fw = flags[1] != 0;
    for (int i = threadIdx.x; i < 224 * 32; i += 256) Ws[i] = ldf(Wl, i, fw);
    int base = blockIdx.x * 8;
    for (int i = threadIdx.x; i < 8 * 224; i += 256) {
        int r = i / 224, k = i % 224;
        int n = base + r;
        float v = 0.f;
        if (n < N) {
            if (k < 128) {
                v = ldf(x, (long long)n * 128 + k, fx);
            } else if (k < 192) {
                v = h1[(long long)n * 64 + (k - 128)];
            } else {
                int c = k - 192;
                float dv = dinv[n];
                v = agg2[(long long)n * 32 + c] + h2x[(long long)n * 32 + c] * dv * dv + ldf(b2, c, fw);
            }
        }
        Cs[i] = v;
    }
    __syncthreads();
    int ln = threadIdx.x >> 5, j = threadIdx.x & 31;
    int n = base + ln;
    float acc = ldf(bl, j, fw);
    const float* cr = &Cs[ln * 224];
#pragma unroll 8
    for (int k = 0; k < 224; k++) acc = fmaf(cr[k], Ws[k * 32 + j], acc);
    float m = acc;
    for (int o = 16; o > 0; o >>= 1) m = fmaxf(m, __shfl_xor(m, o, 32));
    float ex = __expf(acc - m);
    float s = ex;
    for (int o = 16; o > 0; o >>= 1) s += __shfl_xor(s, o, 32);
    float r = acc - m - __logf(s);
    if (n < N) {
        if (fx) ((float*)out)[(long long)n * 32 + j] = r;
        else    ((bf16*)out)[(long long)n * 32 + j] = __float2bfloat16(r);
    }
}

extern "C" void kernel_launch(void* const* d_in, const int* in_sizes, int n_in,
                              void* d_out, int out_size, void* d_ws, size_t ws_size,
                              hipStream_t stream) {
    const void* x  = d_in[0];
    const int*  ei = (const int*)d_in[1];
    const void* W1 = d_in[2];
    const void* b1 = d_in[3];
    const void* W2 = d_in[4];
    const void* b2 = d_in[5];
    const void* Wl = d_in[6];
    const void* bl = d_in[7];

    int N = in_sizes[0] / 128;
    int E = in_sizes[1] / 2;

    // ws layout (fp32 units): [flags 16 | deg N | agg1 N*64 | buf2 N*64]
    // buf2 holds h1x during layer 1; after h1fin it is reused: h2x = buf2[0,N*32), agg2 = buf2[N*32,N*64)
    float* ws   = (float*)d_ws;
    int*   flags = (int*)ws;
    float* deg  = ws + 16;
    float* agg1 = deg + N;
    float* buf2 = agg1 + (size_t)N * 64;
    float* h1x  = buf2;
    float* h2x  = buf2;
    float* agg2 = buf2 + (size_t)N * 32;

    // zero flags + deg + agg1 (contiguous)
    hipMemsetAsync(ws, 0, (16 + (size_t)N * 65) * sizeof(float), stream);

    sniff_kernel<<<3, 256, 0, stream>>>(x, W1, ei, E, flags);
    deg_kernel<<<(E + 255) / 256, 256, 0, stream>>>(ei, E, flags, deg);
    dinv_kernel<<<(N + 255) / 256, 256, 0, stream>>>(deg, N);

    gemm1_kernel<<<(N + 3) / 4, 256, 0, stream>>>(x, W1, flags, h1x, N);
    scatter1_kernel<<<(int)(((long long)E * 16 + 255) / 256), 256, 0, stream>>>(ei, E, flags, deg, h1x, agg1);
    h1fin_kernel<<<(int)(((long long)N * 64 + 255) / 256), 256, 0, stream>>>(agg1, h1x, deg, b1, flags, N);

    // h1x dead now; zero agg2 region before scatter2
    hipMemsetAsync(agg2, 0, (size_t)N * 32 * sizeof(float), stream);

    gemm2_kernel<<<(N + 7) / 8, 256, 0, stream>>>(agg1, W2, flags, h2x, N);
    scatter2_kernel<<<(int)(((long long)E * 8 + 255) / 256), 256, 0, stream>>>(ei, E, flags, deg, h2x, agg2);

    final_kernel<<<(N + 7) / 8, 256, 0, stream>>>(x, agg1, agg2, h2x, deg, b2, Wl, bl, flags, d_out, N);
}